// Round 1
// baseline (410.312 us; speedup 1.0000x reference)
//
#include <hip/hip_runtime.h>
#include <hip/hip_bf16.h>

typedef __attribute__((ext_vector_type(8))) short short8;
typedef __attribute__((ext_vector_type(4))) float f32x4;

#define NB   32
#define HH   112
#define WW   112
#define CIN  128
#define OH_  110
#define OW_  110
#define COUT 256
#define NTAP 9
#define M_TOTAL (NB * OH_ * OW_)   // 387200 = 3025 * 128

__device__ __forceinline__ unsigned short f2bf(float f) {
  union { float f; unsigned u; } v; v.f = f;
  unsigned r = v.u + 0x7fffu + ((v.u >> 16) & 1u);  // round-to-nearest-even
  return (unsigned short)(r >> 16);
}

// Binarize kernel [3,3,128,256] (HWIO) -> bf16 Bt [tap][co][ci] (n-major, k contiguous)
__global__ void prep_weights(const float* __restrict__ kern, unsigned short* __restrict__ bt) {
  int idx = blockIdx.x * 256 + threadIdx.x;
  if (idx >= NTAP * CIN * COUT) return;
  int co   = idx % COUT;
  int rest = idx / COUT;      // tap*128 + ci
  int ci   = rest % CIN;
  int tap  = rest / CIN;
  float kv = kern[idx];
  // match reference bit-for-bit: hs = clip((k/H + 1)/2, 0, 1); r = round-half-even(hs)
  float hs = fminf(fmaxf((kv + 1.0f) * 0.5f, 0.0f), 1.0f);
  float rt = rintf(hs);
  float wb = 2.0f * rt - 1.0f;  // in {-1, +1}
  bt[(tap * COUT + co) * CIN + ci] = f2bf(wb);
}

__global__ __launch_bounds__(512, 2) void bconv(
    const float* __restrict__ x, const unsigned short* __restrict__ bt,
    const float* __restrict__ bias, float* __restrict__ out) {
  extern __shared__ char lds[];
  char* ldsA = lds;            // 128 rows x 128 k bf16, swizzled  (32 KB)
  char* ldsB = lds + 32768;    // 256 rows(n) x 128 k bf16, swizzled (64 KB)

  const int tid  = threadIdx.x;
  const int lane = tid & 63;
  const int wave = tid >> 6;
  const int wm   = wave >> 2;   // 0..1
  const int wn   = wave & 3;    // 0..3
  const int m0   = blockIdx.x * 128;

  // Precompute per-thread A staging addresses (row set is tap-invariant)
  const int c4 = tid & 31;              // float4 index within a 128-float row
  int abase[8];
  int awoff[8];
#pragma unroll
  for (int it = 0; it < 8; ++it) {
    int row = it * 16 + (tid >> 5);
    int m = m0 + row;
    int nimg = m / (OH_ * OW_);
    int r2 = m - nimg * (OH_ * OW_);
    int oh = r2 / OW_;
    int ow = r2 - oh * OW_;
    abase[it] = ((nimg * HH + oh) * WW + ow) * CIN + c4 * 4;
    awoff[it] = row * 256 + ((c4 * 8) ^ ((row & 7) << 4));
  }
  const int brow = tid >> 4;            // B staging: row advance 32/iter
  const int c8   = tid & 15;

  f32x4 acc[4][4];
#pragma unroll
  for (int i = 0; i < 4; ++i)
#pragma unroll
    for (int j = 0; j < 4; ++j) acc[i][j] = (f32x4){0.f, 0.f, 0.f, 0.f};

#pragma unroll 1
  for (int tap = 0; tap < NTAP; ++tap) {
    const int ky = tap / 3;
    const int kx = tap - ky * 3;
    const int xoff = (ky * WW + kx) * CIN;
    __syncthreads();
    // ---- Stage A: 128x128 fp32 -> bf16 ----
#pragma unroll
    for (int it = 0; it < 8; ++it) {
      const float4 xv = *(const float4*)(x + abase[it] + xoff);
      ushort4 h;
      h.x = f2bf(xv.x); h.y = f2bf(xv.y); h.z = f2bf(xv.z); h.w = f2bf(xv.w);
      *(ushort4*)(ldsA + awoff[it]) = h;
    }
    // ---- Stage B: 256x128 bf16 ----
    const unsigned short* btap = bt + tap * (COUT * CIN);
#pragma unroll
    for (int it = 0; it < 8; ++it) {
      int rowN = it * 32 + brow;
      short8 v = *(const short8*)(btap + rowN * CIN + c8 * 8);
      *(short8*)(ldsB + rowN * 256 + ((c8 * 16) ^ ((rowN & 7) << 4))) = v;
    }
    __syncthreads();
    // ---- Compute: K=128 as 4 k-steps of 32 ----
#pragma unroll
    for (int kk = 0; kk < 4; ++kk) {
      const int kb = kk * 64 + ((lane >> 4) << 4);   // byte offset of this lane's 8-k chunk
      short8 af[4], bf[4];
#pragma unroll
      for (int mi = 0; mi < 4; ++mi) {
        int row = wm * 64 + mi * 16 + (lane & 15);
        af[mi] = *(const short8*)(ldsA + row * 256 + (kb ^ ((row & 7) << 4)));
      }
#pragma unroll
      for (int ni = 0; ni < 4; ++ni) {
        int rowN = wn * 64 + ni * 16 + (lane & 15);
        bf[ni] = *(const short8*)(ldsB + rowN * 256 + (kb ^ ((rowN & 7) << 4)));
      }
#pragma unroll
      for (int mi = 0; mi < 4; ++mi)
#pragma unroll
        for (int ni = 0; ni < 4; ++ni)
          acc[mi][ni] = __builtin_amdgcn_mfma_f32_16x16x32_bf16(af[mi], bf[ni], acc[mi][ni], 0, 0, 0);
    }
  }

  // ---- Epilogue: C/D layout col=lane&15, row=(lane>>4)*4+reg ----
  const int  colb = wn * 64 + (lane & 15);
  const long rowb = (long)m0 + wm * 64 + ((lane >> 4) << 2);
#pragma unroll
  for (int ni = 0; ni < 4; ++ni) {
    const int col = colb + ni * 16;
    const float bv = bias[col];
#pragma unroll
    for (int mi = 0; mi < 4; ++mi) {
#pragma unroll
      for (int r = 0; r < 4; ++r) {
        out[(rowb + mi * 16 + r) * COUT + col] = acc[mi][ni][r] + bv;
      }
    }
  }
}

extern "C" void kernel_launch(void* const* d_in, const int* in_sizes, int n_in,
                              void* d_out, int out_size, void* d_ws, size_t ws_size,
                              hipStream_t stream) {
  const float* x    = (const float*)d_in[0];
  const float* kern = (const float*)d_in[1];
  const float* bias = (const float*)d_in[2];
  float* out = (float*)d_out;
  unsigned short* bt = (unsigned short*)d_ws;   // 9*256*128 bf16 = 589824 B

  (void)hipFuncSetAttribute((const void*)bconv,
                            hipFuncAttributeMaxDynamicSharedMemorySize, 98304);

  prep_weights<<<(NTAP * CIN * COUT + 255) / 256, 256, 0, stream>>>(kern, bt);
  bconv<<<dim3(M_TOTAL / 128), dim3(512), 98304, stream>>>(x, bt, bias, out);
}